// Round 9
// baseline (1259.124 us; speedup 1.0000x reference)
//
#include <hip/hip_runtime.h>

#define N_NODES 4096
#define HID 512
#define HEADS 8
#define DH 64
#define EPS 1e-5f
#define MAXD 128

typedef __attribute__((ext_vector_type(8))) short bf16x8;
typedef __attribute__((ext_vector_type(4))) float f32x4;

__device__ __forceinline__ unsigned short f2bf(float f) {
    unsigned int u = __float_as_uint(f);
    unsigned int r = (u + 0x7FFFu + ((u >> 16) & 1u)) >> 16;   // RNE
    return (unsigned short)r;
}
__device__ __forceinline__ float blo(unsigned int u) {        // low bf16 -> f32
    return __uint_as_float(u << 16);
}
__device__ __forceinline__ float bhi(unsigned int u) {        // high bf16 -> f32
    return __uint_as_float(u & 0xffff0000u);
}

__device__ __forceinline__ void gld_lds16(const void* g, void* l) {
    __builtin_amdgcn_global_load_lds(
        (const __attribute__((address_space(1))) unsigned int*)g,
        (__attribute__((address_space(3))) unsigned int*)l, 16, 0, 0);
}

// ---------------------------------------------------------------------------
// Hybrid bf16 MFMA GEMM (synthesis of R6 + R8 evidence):
//   - B (weights, shared by all 4 M-stacked waves) staged via global_load_lds
//     into 8KB LDS with the R6-proven conflict-free XOR swizzle; barrier pair
//     gates ONLY these 2 DMA instructions.
//   - A (no cross-wave reuse) loaded straight global->VGPR, software
//     double-buffered one K-step ahead; plain loads don't trigger the
//     pre-barrier vmcnt(0) drain, so they pipeline across iterations.
//   - Grids as R6 (>=512 blocks); block=256thr/4 waves stacked on M.
// AFRAG: A in fragment-packed layout (hb) -> 1KB coalesced wave loads.
// EPI: 0 bias->bf16 ; 1 bias+relu->bf16 ; 2 bias+res(f32)->f32 + stats ;
//      3 bias+res(bf16)->f32 + stats
// ---------------------------------------------------------------------------
template<int TM, int EPI, bool AFRAG>
__global__ __launch_bounds__(256) void gemm_h(
    const unsigned short* __restrict__ Xb, const unsigned short* __restrict__ Wt,
    const float* __restrict__ bias, const float* __restrict__ res,
    const unsigned short* __restrict__ resb,
    float* __restrict__ outf, unsigned short* __restrict__ outb,
    float* __restrict__ sum, float* __restrict__ sumsq,
    int K, int Nc)
{
    constexpr int WM = TM / 64;                    // mfma row-tiles per wave
    __shared__ __align__(16) unsigned short Bs[64 * 64];   // 8 KB

    const int tid = threadIdx.x;
    const int lane = tid & 63;
    const int wv = tid >> 6;
    const int m0 = blockIdx.y * TM, n0 = blockIdx.x * 64;
    const int lc = lane & 15, lq = lane >> 4;
    const int wrow = m0 + wv * (TM / 4);

    const int srow = tid >> 3;                     // 0..31 (instr2 adds 32)
    const int schunk = (tid & 7) ^ (srow & 7);     // swizzled global k-chunk
    unsigned short* ldsB = Bs + tid * 8;

    const int KC = K >> 5;
    const unsigned short* paf = Xb + ((size_t)(wrow >> 4) * KC) * 512 + lane * 8;
    const unsigned short* par = Xb + (size_t)(wrow + lc) * K + lq * 8;

    bf16x8 afb[2][WM][2];
    f32x4 acc[WM][4] = {};

    auto loadA = [&](int s, int buf) {
        #pragma unroll
        for (int i = 0; i < WM; ++i)
            #pragma unroll
            for (int h = 0; h < 2; ++h)
                afb[buf][i][h] = AFRAG
                    ? *(const bf16x8*)(paf + ((size_t)i * KC + 2 * s + h) * 512)
                    : *(const bf16x8*)(par + (size_t)(i * 16) * K + s * 64 + h * 32);
    };

    loadA(0, 0);
    const int NS = K >> 6;
    for (int s = 0; s < NS; ++s) {
        const unsigned short* gB = Wt + (size_t)(n0 + srow) * K + s * 64 + schunk * 8;
        gld_lds16(gB, ldsB);
        gld_lds16(gB + (size_t)32 * K, ldsB + 2048);
        __syncthreads();

        if (s + 1 < NS) loadA(s + 1, (s & 1) ^ 1);

        bf16x8 bfr[4][2];
        #pragma unroll
        for (int j = 0; j < 4; ++j)
            #pragma unroll
            for (int h = 0; h < 2; ++h)
                bfr[j][h] = *(const bf16x8*)&Bs[(j * 16 + lc) * 64 + ((h * 4 + lq) ^ (lc & 7)) * 8];

        const int cur = s & 1;
        #pragma unroll
        for (int h = 0; h < 2; ++h)
            #pragma unroll
            for (int i = 0; i < WM; ++i)
                #pragma unroll
                for (int j = 0; j < 4; ++j)
                    acc[i][j] = __builtin_amdgcn_mfma_f32_16x16x32_bf16(
                        afb[cur][i][h], bfr[j][h], acc[i][j], 0, 0, 0);
        __syncthreads();
    }

    float cs[4] = {}, css[4] = {};
    #pragma unroll
    for (int i = 0; i < WM; ++i) {
        #pragma unroll
        for (int j = 0; j < 4; ++j) {
            const int gr0 = wrow + i * 16 + lq * 4;
            const int gc = n0 + j * 16 + lc;
            const float bi = bias[gc];
            #pragma unroll
            for (int r = 0; r < 4; ++r) {
                float val = acc[i][j][r] + bi;
                size_t off = (size_t)(gr0 + r) * Nc + gc;
                if (EPI == 0)      outb[off] = f2bf(val);
                else if (EPI == 1) outb[off] = f2bf(fmaxf(val, 0.f));
                else {
                    if (EPI == 2) val += res[off];
                    else          val += blo((unsigned int)resb[off]);
                    outf[off] = val;
                    cs[j] += val; css[j] += val * val;
                }
            }
        }
    }
    if (EPI >= 2) {
        #pragma unroll
        for (int j = 0; j < 4; ++j) {
            float s = cs[j], ss = css[j];
            s += __shfl_xor(s, 16); s += __shfl_xor(s, 32);
            ss += __shfl_xor(ss, 16); ss += __shfl_xor(ss, 32);
            if (lq == 0) {
                const int gc = n0 + j * 16 + lc;
                atomicAdd(&sum[gc], s);
                atomicAdd(&sumsq[gc], ss);
            }
        }
    }
}

// ---------------------------------------------------------------------------
// Fused prep: z=0..5 weight transpose -> K-major bf16 (for LDS-staged B);
// z=6 h -> FRAGMENT-PACKED bf16 (QKV A operand); z=7 bias concat + stat zero
// ---------------------------------------------------------------------------
__global__ __launch_bounds__(256) void prep_all(
    const float* __restrict__ Wq, const float* __restrict__ Wk,
    const float* __restrict__ Wv, const float* __restrict__ Wo,
    const float* __restrict__ W1, const float* __restrict__ W2,
    const float* __restrict__ h,
    const float* __restrict__ bq, const float* __restrict__ bk,
    const float* __restrict__ bv,
    unsigned short* __restrict__ wqkvT, unsigned short* __restrict__ woT,
    unsigned short* __restrict__ w1T, unsigned short* __restrict__ w2T,
    unsigned int* __restrict__ hb, float* __restrict__ bqkv,
    float* __restrict__ st)
{
    const int z = blockIdx.z;
    if (z < 6) {
        const float* in; unsigned short* out; int R, C;
        switch (z) {
            case 0: in = Wq; out = wqkvT;          R = 512;  C = 512;  break;
            case 1: in = Wk; out = wqkvT + 262144; R = 512;  C = 512;  break;
            case 2: in = Wv; out = wqkvT + 524288; R = 512;  C = 512;  break;
            case 3: in = Wo; out = woT;            R = 512;  C = 512;  break;
            case 4: in = W1; out = w1T;            R = 512;  C = 1024; break;
            default: in = W2; out = w2T;           R = 1024; C = 512;  break;
        }
        const int bc = blockIdx.x * 32, br = blockIdx.y * 32;
        if (bc >= C || br >= R) return;
        __shared__ float tile[32][33];
        const int tx = threadIdx.x & 31, ty = threadIdx.x >> 5;
        #pragma unroll
        for (int r = ty; r < 32; r += 8)
            tile[r][tx] = in[(size_t)(br + r) * C + bc + tx];
        __syncthreads();
        #pragma unroll
        for (int r = ty; r < 32; r += 8)
            out[(size_t)(bc + r) * R + br + tx] = f2bf(tile[tx][r]);
    } else if (z == 6) {
        // h (4096x512 f32) -> fragment-packed bf16: one thread = 8 k of a row
        const int blk = blockIdx.y * 32 + blockIdx.x;
        const int i = blk * 512 + threadIdx.x * 2;   // even float4 index
        const float4* in4 = (const float4*)h;
        float4 f0 = in4[i], f1 = in4[i + 1];
        uint4 w;
        w.x = (unsigned int)f2bf(f0.x) | ((unsigned int)f2bf(f0.y) << 16);
        w.y = (unsigned int)f2bf(f0.z) | ((unsigned int)f2bf(f0.w) << 16);
        w.z = (unsigned int)f2bf(f1.x) | ((unsigned int)f2bf(f1.y) << 16);
        w.w = (unsigned int)f2bf(f1.z) | ((unsigned int)f2bf(f1.w) << 16);
        const int m = i >> 7, k = (i & 127) * 4;     // k % 8 == 0
        const size_t off_u4 = ((size_t)(m >> 4) * 16 + (k >> 5)) * 64
                            + ((k >> 3) & 3) * 16 + (m & 15);
        ((uint4*)hb)[off_u4] = w;
    } else {
        const int blk = blockIdx.y * 32 + blockIdx.x;
        const int i = blk * 256 + threadIdx.x;
        if (i < 1536) bqkv[i] = i < 512 ? bq[i] : (i < 1024 ? bk[i - 512] : bv[i - 1024]);
        if (i < 2048) st[i] = 0.0f;
    }
}

// ---------------------------------------------------------------------------
// Sparse attention v6: v5 (stable at ~44us) + widened accumulate phase:
// uint4 V loads, 8 neighbors/iter (8 nbr-lanes x 8 dims/lane), 1-deep
// prefetch. Score/softmax/adjacency phases unchanged.
// NO bulk K/V LDS staging (v3's 1-block/CU cliff: 123us vs 65us).
// ---------------------------------------------------------------------------
__global__ __launch_bounds__(256) void sparse_attn6(
    const float* __restrict__ A, const unsigned short* __restrict__ qkv,
    unsigned short* __restrict__ o)
{
    const int n = blockIdx.x;
    const int tid = threadIdx.x;
    const int wv = tid >> 6, lane = tid & 63;

    __shared__ int s_idx[MAXD];
    __shared__ float s_p[8][MAXD];
    __shared__ int s_cnt[4];

    // ---- Phase A: inline adjacency ----
    const float4* r4 = (const float4*)(A + (size_t)n * N_NODES);
    float4 av[4];
    #pragma unroll
    for (int t = 0; t < 4; ++t)
        av[t] = r4[wv * 256 + t * 64 + lane];

    const unsigned long long lt = (1ull << lane) - 1ull;
    int cnt = 0;
    #pragma unroll
    for (int t = 0; t < 4; ++t) {
        #pragma unroll
        for (int b = 0; b < 4; ++b) {
            float vb = (b == 0) ? av[t].x : (b == 1) ? av[t].y : (b == 2) ? av[t].z : av[t].w;
            cnt += __popcll(__ballot(vb > 0.0f));
        }
    }
    if (lane == 0) s_cnt[wv] = cnt;
    __syncthreads();
    int base = 0, total = 0;
    #pragma unroll
    for (int w = 0; w < 4; ++w) {
        if (w < wv) base += s_cnt[w];
        total += s_cnt[w];
    }
    const int d = total < MAXD ? total : MAXD;
    #pragma unroll
    for (int t = 0; t < 4; ++t) {
        #pragma unroll
        for (int b = 0; b < 4; ++b) {
            float vb = (b == 0) ? av[t].x : (b == 1) ? av[t].y : (b == 2) ? av[t].z : av[t].w;
            unsigned long long m = __ballot(vb > 0.0f);
            if (vb > 0.0f) {
                int p = base + __popcll(m & lt);
                if (p < MAXD) s_idx[p] = wv * 1024 + t * 256 + lane * 4 + b;
            }
            base += __popcll(m);
        }
    }
    __syncthreads();

    // ---- Phase B: scores ----
    const int jl = lane >> 3;      // neighbor sub-index (score), 0..7
    const int dgs = lane & 7;      // dim-group of 8 (score)
    const int h0 = wv, h1 = wv + 4;

    const unsigned short* qp = qkv + (size_t)n * 1536 + dgs * 8;
    uint4 qa = *(const uint4*)(qp + h0 * 64);
    uint4 qb = *(const uint4*)(qp + h1 * 64);
    const float a0 = blo(qa.x), a1 = bhi(qa.x), a2 = blo(qa.y), a3 = bhi(qa.y);
    const float a4 = blo(qa.z), a5 = bhi(qa.z), a6 = blo(qa.w), a7 = bhi(qa.w);
    const float b0 = blo(qb.x), b1 = bhi(qb.x), b2 = blo(qb.y), b3 = bhi(qb.y);
    const float b4 = blo(qb.z), b5 = bhi(qb.z), b6 = blo(qb.w), b7 = bhi(qb.w);

    uint4 ka = {0, 0, 0, 0}, kb = {0, 0, 0, 0};
    if (jl < d) {
        const unsigned short* p = qkv + (size_t)s_idx[jl] * 1536 + 512 + dgs * 8;
        ka = *(const uint4*)(p + h0 * 64);
        kb = *(const uint4*)(p + h1 * 64);
    }
    for (int j0 = 0; j0 < d; j0 += 8) {
        const uint4 ca = ka, cb = kb;
        const int jn = j0 + 8 + jl;
        if (jn < d) {
            const unsigned short* p = qkv + (size_t)s_idx[jn] * 1536 + 512 + dgs * 8;
            ka = *(const uint4*)(p + h0 * 64);
            kb = *(const uint4*)(p + h1 * 64);
        }
        const int jc = j0 + jl;
        float s0 = 0.f, s1 = 0.f;
        if (jc < d) {
            s0 = a0 * blo(ca.x) + a1 * bhi(ca.x) + a2 * blo(ca.y) + a3 * bhi(ca.y)
               + a4 * blo(ca.z) + a5 * bhi(ca.z) + a6 * blo(ca.w) + a7 * bhi(ca.w);
            s1 = b0 * blo(cb.x) + b1 * bhi(cb.x) + b2 * blo(cb.y) + b3 * bhi(cb.y)
               + b4 * blo(cb.z) + b5 * bhi(cb.z) + b6 * blo(cb.w) + b7 * bhi(cb.w);
        }
        s0 += __shfl_xor(s0, 1); s1 += __shfl_xor(s1, 1);
        s0 += __shfl_xor(s0, 2); s1 += __shfl_xor(s1, 2);
        s0 += __shfl_xor(s0, 4); s1 += __shfl_xor(s1, 4);
        if (dgs == 0 && jc < d) {
            s_p[h0][jc] = s0 * 0.125f;    // 1/sqrt(64)
            s_p[h1][jc] = s1 * 0.125f;
        }
    }

    // ---- softmax per head ----
    float inv0, inv1;
    #pragma unroll
    for (int hh = 0; hh < 2; ++hh) {
        float* sp = s_p[hh ? h1 : h0];
        float mx = -1e30f;
        for (int j = lane; j < d; j += 64) mx = fmaxf(mx, sp[j]);
        #pragma unroll
        for (int off = 32; off; off >>= 1) mx = fmaxf(mx, __shfl_xor(mx, off));
        float sum = 0.f;
        for (int j = lane; j < d; j += 64) {
            float e = __expf(sp[j] - mx);
            sp[j] = e;
            sum += e;
        }
        #pragma unroll
        for (int off = 32; off; off >>= 1) sum += __shfl_xor(sum, off);
        if (hh) inv1 = 1.0f / sum; else inv0 = 1.0f / sum;
    }

    // ---- accumulate o: 8 nbr-lanes x 8 dims/lane, uint4, prefetched ----
    float xa[8] = {}, ya[8] = {};
    uint4 va = {0, 0, 0, 0}, vb = {0, 0, 0, 0};
    if (jl < d) {
        const unsigned short* p = qkv + (size_t)s_idx[jl] * 1536 + 1024 + dgs * 8;
        va = *(const uint4*)(p + h0 * 64);
        vb = *(const uint4*)(p + h1 * 64);
    }
    for (int j0 = 0; j0 < d; j0 += 8) {
        const uint4 ca = va, cb = vb;
        const int jn = j0 + 8 + jl;
        if (jn < d) {
            const unsigned short* p = qkv + (size_t)s_idx[jn] * 1536 + 1024 + dgs * 8;
            va = *(const uint4*)(p + h0 * 64);
            vb = *(const uint4*)(p + h1 * 64);
        }
        const int jc = j0 + jl;
        if (jc < d) {
            const float p0 = s_p[h0][jc], p1 = s_p[h1][jc];
            xa[0] += p0 * blo(ca.x); xa[1] += p0 * bhi(ca.x);
            xa[2] += p0 * blo(ca.y); xa[3] += p0 * bhi(ca.y);
            xa[4] += p0 * blo(ca.z); xa[5] += p0 * bhi(ca.z);
            xa[6] += p0 * blo(ca.w); xa[7] += p0 * bhi(ca.w);
            ya[0] += p1 * blo(cb.x); ya[1] += p1 * bhi(cb.x);
            ya[2] += p1 * blo(cb.y); ya[3] += p1 * bhi(cb.y);
            ya[4] += p1 * blo(cb.z); ya[5] += p1 * bhi(cb.z);
            ya[6] += p1 * blo(cb.w); ya[7] += p1 * bhi(cb.w);
        }
    }
    #pragma unroll
    for (int t = 0; t < 8; ++t) {
        xa[t] += __shfl_xor(xa[t], 8);
        xa[t] += __shfl_xor(xa[t], 16);
        xa[t] += __shfl_xor(xa[t], 32);
        ya[t] += __shfl_xor(ya[t], 8);
        ya[t] += __shfl_xor(ya[t], 16);
        ya[t] += __shfl_xor(ya[t], 32);
    }
    if (jl == 0) {
        uint4 w0, w1;
        w0.x = (unsigned int)f2bf(xa[0] * inv0) | ((unsigned int)f2bf(xa[1] * inv0) << 16);
        w0.y = (unsigned int)f2bf(xa[2] * inv0) | ((unsigned int)f2bf(xa[3] * inv0) << 16);
        w0.z = (unsigned int)f2bf(xa[4] * inv0) | ((unsigned int)f2bf(xa[5] * inv0) << 16);
        w0.w = (unsigned int)f2bf(xa[6] * inv0) | ((unsigned int)f2bf(xa[7] * inv0) << 16);
        w1.x = (unsigned int)f2bf(ya[0] * inv1) | ((unsigned int)f2bf(ya[1] * inv1) << 16);
        w1.y = (unsigned int)f2bf(ya[2] * inv1) | ((unsigned int)f2bf(ya[3] * inv1) << 16);
        w1.z = (unsigned int)f2bf(ya[4] * inv1) | ((unsigned int)f2bf(ya[5] * inv1) << 16);
        w1.w = (unsigned int)f2bf(ya[6] * inv1) | ((unsigned int)f2bf(ya[7] * inv1) << 16);
        *(uint4*)(o + (size_t)n * 512 + h0 * 64 + dgs * 8) = w0;
        *(uint4*)(o + (size_t)n * 512 + h1 * 64 + dgs * 8) = w1;
    }
}

// ---------------------------------------------------------------------------
// BatchNorm apply, float4 (stats fused in the preceding GEMM epilogue).
// ---------------------------------------------------------------------------
__global__ __launch_bounds__(256) void bn_apply4(
    const float4* __restrict__ x, const float* __restrict__ sum,
    const float* __restrict__ sumsq, const float* __restrict__ g,
    const float* __restrict__ b, float4* __restrict__ yf,
    uint2* __restrict__ yb)
{
    const int i = blockIdx.x * 256 + threadIdx.x;
    const int c4 = i & 127;
    const float4 s4 = ((const float4*)sum)[c4];
    const float4 q4 = ((const float4*)sumsq)[c4];
    const float4 g4 = ((const float4*)g)[c4];
    const float4 b4 = ((const float4*)b)[c4];
    const float4 xv = x[i];
    const float kN = 1.0f / N_NODES;
    float4 r;
    { float m = s4.x * kN; r.x = g4.x * (xv.x - m) * rsqrtf(q4.x * kN - m * m + EPS) + b4.x; }
    { float m = s4.y * kN; r.y = g4.y * (xv.y - m) * rsqrtf(q4.y * kN - m * m + EPS) + b4.y; }
    { float m = s4.z * kN; r.z = g4.z * (xv.z - m) * rsqrtf(q4.z * kN - m * m + EPS) + b4.z; }
    { float m = s4.w * kN; r.w = g4.w * (xv.w - m) * rsqrtf(q4.w * kN - m * m + EPS) + b4.w; }
    if (yf) yf[i] = r;
    if (yb) {
        uint2 p;
        p.x = (unsigned int)f2bf(r.x) | ((unsigned int)f2bf(r.y) << 16);
        p.y = (unsigned int)f2bf(r.z) | ((unsigned int)f2bf(r.w) << 16);
        yb[i] = p;
    }
}

// ---------------------------------------------------------------------------

extern "C" void kernel_launch(void* const* d_in, const int* in_sizes, int n_in,
                              void* d_out, int out_size, void* d_ws, size_t ws_size,
                              hipStream_t stream)
{
    const float* A   = (const float*)d_in[0];
    const float* h   = (const float*)d_in[1];
    const float* Wq  = (const float*)d_in[2];
    const float* bq  = (const float*)d_in[3];
    const float* Wk  = (const float*)d_in[4];
    const float* bk  = (const float*)d_in[5];
    const float* Wv  = (const float*)d_in[6];
    const float* bv  = (const float*)d_in[7];
    const float* Wo  = (const float*)d_in[8];
    const float* bo  = (const float*)d_in[9];
    const float* g1  = (const float*)d_in[10];
    const float* b1g = (const float*)d_in[11];
    const float* g2  = (const float*)d_in[12];
    const float* b2g = (const float*)d_in[13];
    const float* W1  = (const float*)d_in[14];
    const float* b1  = (const float*)d_in[15];
    const float* W2  = (const float*)d_in[16];
    const float* b2  = (const float*)d_in[17];
    float* out = (float*)d_out;

    float* ws = (float*)d_ws;
    unsigned short* hb    = (unsigned short*)(ws);               // 4096x512 bf16 (frag)
    unsigned short* qkvb  = (unsigned short*)(ws + 1048576);     // 4096x1536 bf16
    unsigned short* o_bf  = (unsigned short*)(ws + 4194304);     // 4096x512 bf16
    unsigned short* wqkvT = (unsigned short*)(ws + 5242880);     // 1536x512 bf16 K-major
    unsigned short* woT   = (unsigned short*)(ws + 5636096);     // 512x512 bf16 K-major
    unsigned short* w1T   = (unsigned short*)(ws + 5767168);     // 1024x512 bf16 K-major
    unsigned short* w2T   = (unsigned short*)(ws + 6029312);     // 512x1024 bf16 K-major
    unsigned short* t_b   = (unsigned short*)(ws + 6291456);     // 4096x1024 bf16
    float* x1   = ws + 8388608;                                   // 4096x512 f32
    float* x2   = ws + 10485760;                                  // 4096x512 f32
    unsigned short* xb1_b = (unsigned short*)(ws + 12582912);    // 4096x512 bf16
    float* bqkv = ws + 13631488;                                  // 1536
    float* st   = ws + 13633024;                                  // 2048

    // --- fused prep ---
    prep_all<<<dim3(32, 32, 8), dim3(256), 0, stream>>>(
        Wq, Wk, Wv, Wo, W1, W2, h, bq, bk, bv,
        wqkvT, woT, w1T, w2T, (unsigned int*)hb, bqkv, st);

    // --- fused QKV projection: 768 blocks (3/CU), frag-packed A ---
    gemm_h<128, 0, true><<<dim3(24, 32), dim3(256), 0, stream>>>(
        hb, wqkvT, bqkv, nullptr, nullptr, nullptr, qkvb, nullptr, nullptr, 512, 1536);

    // --- sparse masked attention (inline adjacency) ---
    sparse_attn6<<<dim3(N_NODES), dim3(256), 0, stream>>>(A, qkvb, o_bf);

    // --- O projection + residual(h,f32) + BN1 stats: 512 blocks ---
    gemm_h<64, 2, false><<<dim3(8, 64), dim3(256), 0, stream>>>(
        o_bf, woT, bo, h, nullptr, x1, nullptr, st, st + 512, 512, 512);

    // --- BN1 apply -> bf16 only ---
    bn_apply4<<<dim3(2048), dim3(256), 0, stream>>>(
        (const float4*)x1, st, st + 512, g1, b1g, nullptr, (uint2*)xb1_b);

    // --- FFN1: 512 blocks ---
    gemm_h<128, 1, false><<<dim3(16, 32), dim3(256), 0, stream>>>(
        xb1_b, w1T, b1, nullptr, nullptr, nullptr, t_b, nullptr, nullptr, 512, 1024);

    // --- FFN2 + residual(xb1,bf16) + BN2 stats: 512 blocks ---
    gemm_h<64, 3, false><<<dim3(8, 64), dim3(256), 0, stream>>>(
        t_b, w2T, b2, nullptr, xb1_b, x2, nullptr, st + 1024, st + 1536, 1024, 512);

    // --- BN2 apply -> out ---
    bn_apply4<<<dim3(2048), dim3(256), 0, stream>>>(
        (const float4*)x2, st + 1024, st + 1536, g2, b2g, (float4*)out, nullptr);

    (void)in_sizes; (void)n_in; (void)out_size; (void)ws_size;
}

// Round 10
// 233.578 us; speedup vs baseline: 5.3906x; 5.3906x over previous
//
#include <hip/hip_runtime.h>

#define N_NODES 4096
#define HID 512
#define HEADS 8
#define DH 64
#define EPS 1e-5f
#define MAXD 128

typedef __attribute__((ext_vector_type(8))) short bf16x8;
typedef __attribute__((ext_vector_type(4))) float f32x4;

__device__ __forceinline__ unsigned short f2bf(float f) {
    unsigned int u = __float_as_uint(f);
    unsigned int r = (u + 0x7FFFu + ((u >> 16) & 1u)) >> 16;   // RNE
    return (unsigned short)r;
}
__device__ __forceinline__ float blo(unsigned int u) {        // low bf16 -> f32
    return __uint_as_float(u << 16);
}
__device__ __forceinline__ float bhi(unsigned int u) {        // high bf16 -> f32
    return __uint_as_float(u & 0xffff0000u);
}

__device__ __forceinline__ void gld_lds16(const void* g, void* l) {
    __builtin_amdgcn_global_load_lds(
        (const __attribute__((address_space(1))) unsigned int*)g,
        (__attribute__((address_space(3))) unsigned int*)l, 16, 0, 0);
}

// ---------------------------------------------------------------------------
// Hybrid bf16 MFMA GEMM (R6+R8 synthesis, R9 spill-bug fixed):
//   - B (shared by all 4 M-stacked waves) staged via global_load_lds into
//     8KB LDS, R6-proven conflict-free XOR swizzle; barrier pair gates only
//     these 2 DMA instructions.
//   - A (no cross-wave reuse) loaded straight global->VGPR, double-buffered
//     one K-step ahead.
//   - K is a TEMPLATE parameter and the K-loop is fully unrolled: all
//     afb[buf] indices must constant-fold, else the double-buffer lands in
//     scratch (R9: runtime `s&1` index -> 511us/dispatch, MfmaUtil 0.5%).
// EPI: 0 bias->bf16 ; 1 bias+relu->bf16 ; 2 bias+res(f32)->f32 + stats ;
//      3 bias+res(bf16)->f32 + stats
// ---------------------------------------------------------------------------
template<int TM, int EPI, bool AFRAG, int K>
__global__ __launch_bounds__(256) void gemm_h(
    const unsigned short* __restrict__ Xb, const unsigned short* __restrict__ Wt,
    const float* __restrict__ bias, const float* __restrict__ res,
    const unsigned short* __restrict__ resb,
    float* __restrict__ outf, unsigned short* __restrict__ outb,
    float* __restrict__ sum, float* __restrict__ sumsq, int Nc)
{
    constexpr int WM = TM / 64;                    // mfma row-tiles per wave
    constexpr int KC = K >> 5;                     // 32-elem k-chunks
    constexpr int NS = K >> 6;                     // 64-elem k-steps
    __shared__ __align__(16) unsigned short Bs[64 * 64];   // 8 KB

    const int tid = threadIdx.x;
    const int lane = tid & 63;
    const int wv = tid >> 6;
    const int m0 = blockIdx.y * TM, n0 = blockIdx.x * 64;
    const int lc = lane & 15, lq = lane >> 4;
    const int wrow = m0 + wv * (TM / 4);

    const int srow = tid >> 3;                     // 0..31 (instr2 adds 32)
    const int schunk = (tid & 7) ^ (srow & 7);     // swizzled global k-chunk
    unsigned short* ldsB = Bs + tid * 8;

    const unsigned short* paf = Xb + ((size_t)(wrow >> 4) * KC) * 512 + lane * 8;
    const unsigned short* par = Xb + (size_t)(wrow + lc) * K + lq * 8;

    bf16x8 afb[2][WM][2];
    f32x4 acc[WM][4] = {};

#define LOAD_A(S, BUF)                                                          \
    _Pragma("unroll")                                                           \
    for (int i = 0; i < WM; ++i)                                                \
        _Pragma("unroll")                                                       \
        for (int h = 0; h < 2; ++h)                                             \
            afb[BUF][i][h] = AFRAG                                              \
                ? *(const bf16x8*)(paf + ((size_t)i * KC + 2 * (S) + h) * 512)  \
                : *(const bf16x8*)(par + (size_t)(i * 16) * K + (S) * 64 + h * 32);

    LOAD_A(0, 0)
    #pragma unroll
    for (int s = 0; s < NS; ++s) {
        const unsigned short* gB = Wt + (size_t)(n0 + srow) * K + s * 64 + schunk * 8;
        gld_lds16(gB, ldsB);
        gld_lds16(gB + (size_t)32 * K, ldsB + 2048);
        __syncthreads();

        if (s + 1 < NS) { LOAD_A(s + 1, ((s & 1) ^ 1)) }

        bf16x8 bfr[4][2];
        #pragma unroll
        for (int j = 0; j < 4; ++j)
            #pragma unroll
            for (int h = 0; h < 2; ++h)
                bfr[j][h] = *(const bf16x8*)&Bs[(j * 16 + lc) * 64 + ((h * 4 + lq) ^ (lc & 7)) * 8];

        #pragma unroll
        for (int h = 0; h < 2; ++h)
            #pragma unroll
            for (int i = 0; i < WM; ++i)
                #pragma unroll
                for (int j = 0; j < 4; ++j)
                    acc[i][j] = __builtin_amdgcn_mfma_f32_16x16x32_bf16(
                        afb[s & 1][i][h], bfr[j][h], acc[i][j], 0, 0, 0);
        __syncthreads();
    }
#undef LOAD_A

    float cs[4] = {}, css[4] = {};
    #pragma unroll
    for (int i = 0; i < WM; ++i) {
        #pragma unroll
        for (int j = 0; j < 4; ++j) {
            const int gr0 = wrow + i * 16 + lq * 4;
            const int gc = n0 + j * 16 + lc;
            const float bi = bias[gc];
            #pragma unroll
            for (int r = 0; r < 4; ++r) {
                float val = acc[i][j][r] + bi;
                size_t off = (size_t)(gr0 + r) * Nc + gc;
                if (EPI == 0)      outb[off] = f2bf(val);
                else if (EPI == 1) outb[off] = f2bf(fmaxf(val, 0.f));
                else {
                    if (EPI == 2) val += res[off];
                    else          val += blo((unsigned int)resb[off]);
                    outf[off] = val;
                    cs[j] += val; css[j] += val * val;
                }
            }
        }
    }
    if (EPI >= 2) {
        #pragma unroll
        for (int j = 0; j < 4; ++j) {
            float s = cs[j], ss = css[j];
            s += __shfl_xor(s, 16); s += __shfl_xor(s, 32);
            ss += __shfl_xor(ss, 16); ss += __shfl_xor(ss, 32);
            if (lq == 0) {
                const int gc = n0 + j * 16 + lc;
                atomicAdd(&sum[gc], s);
                atomicAdd(&sumsq[gc], ss);
            }
        }
    }
}

// ---------------------------------------------------------------------------
// Fused prep: z=0..5 weight transpose -> K-major bf16 (for LDS-staged B);
// z=6 h -> FRAGMENT-PACKED bf16 (QKV A operand); z=7 bias concat + stat zero
// ---------------------------------------------------------------------------
__global__ __launch_bounds__(256) void prep_all(
    const float* __restrict__ Wq, const float* __restrict__ Wk,
    const float* __restrict__ Wv, const float* __restrict__ Wo,
    const float* __restrict__ W1, const float* __restrict__ W2,
    const float* __restrict__ h,
    const float* __restrict__ bq, const float* __restrict__ bk,
    const float* __restrict__ bv,
    unsigned short* __restrict__ wqkvT, unsigned short* __restrict__ woT,
    unsigned short* __restrict__ w1T, unsigned short* __restrict__ w2T,
    unsigned int* __restrict__ hb, float* __restrict__ bqkv,
    float* __restrict__ st)
{
    const int z = blockIdx.z;
    if (z < 6) {
        const float* in; unsigned short* out; int R, C;
        switch (z) {
            case 0: in = Wq; out = wqkvT;          R = 512;  C = 512;  break;
            case 1: in = Wk; out = wqkvT + 262144; R = 512;  C = 512;  break;
            case 2: in = Wv; out = wqkvT + 524288; R = 512;  C = 512;  break;
            case 3: in = Wo; out = woT;            R = 512;  C = 512;  break;
            case 4: in = W1; out = w1T;            R = 512;  C = 1024; break;
            default: in = W2; out = w2T;           R = 1024; C = 512;  break;
        }
        const int bc = blockIdx.x * 32, br = blockIdx.y * 32;
        if (bc >= C || br >= R) return;
        __shared__ float tile[32][33];
        const int tx = threadIdx.x & 31, ty = threadIdx.x >> 5;
        #pragma unroll
        for (int r = ty; r < 32; r += 8)
            tile[r][tx] = in[(size_t)(br + r) * C + bc + tx];
        __syncthreads();
        #pragma unroll
        for (int r = ty; r < 32; r += 8)
            out[(size_t)(bc + r) * R + br + tx] = f2bf(tile[tx][r]);
    } else if (z == 6) {
        // h (4096x512 f32) -> fragment-packed bf16: one thread = 8 k of a row
        const int blk = blockIdx.y * 32 + blockIdx.x;
        const int i = blk * 512 + threadIdx.x * 2;   // even float4 index
        const float4* in4 = (const float4*)h;
        float4 f0 = in4[i], f1 = in4[i + 1];
        uint4 w;
        w.x = (unsigned int)f2bf(f0.x) | ((unsigned int)f2bf(f0.y) << 16);
        w.y = (unsigned int)f2bf(f0.z) | ((unsigned int)f2bf(f0.w) << 16);
        w.z = (unsigned int)f2bf(f1.x) | ((unsigned int)f2bf(f1.y) << 16);
        w.w = (unsigned int)f2bf(f1.z) | ((unsigned int)f2bf(f1.w) << 16);
        const int m = i >> 7, k = (i & 127) * 4;     // k % 8 == 0
        const size_t off_u4 = ((size_t)(m >> 4) * 16 + (k >> 5)) * 64
                            + ((k >> 3) & 3) * 16 + (m & 15);
        ((uint4*)hb)[off_u4] = w;
    } else {
        const int blk = blockIdx.y * 32 + blockIdx.x;
        const int i = blk * 256 + threadIdx.x;
        if (i < 1536) bqkv[i] = i < 512 ? bq[i] : (i < 1024 ? bk[i - 512] : bv[i - 1024]);
        if (i < 2048) st[i] = 0.0f;
    }
}

// ---------------------------------------------------------------------------
// Sparse attention v6: v5 core (stable ~44us) + widened uint4 accumulate
// (8 nbr-lanes x 8 dims/lane, 1-deep prefetch).
// NO bulk K/V LDS staging (v3's 1-block/CU cliff: 123us vs 65us).
// ---------------------------------------------------------------------------
__global__ __launch_bounds__(256) void sparse_attn6(
    const float* __restrict__ A, const unsigned short* __restrict__ qkv,
    unsigned short* __restrict__ o)
{
    const int n = blockIdx.x;
    const int tid = threadIdx.x;
    const int wv = tid >> 6, lane = tid & 63;

    __shared__ int s_idx[MAXD];
    __shared__ float s_p[8][MAXD];
    __shared__ int s_cnt[4];

    // ---- Phase A: inline adjacency ----
    const float4* r4 = (const float4*)(A + (size_t)n * N_NODES);
    float4 av[4];
    #pragma unroll
    for (int t = 0; t < 4; ++t)
        av[t] = r4[wv * 256 + t * 64 + lane];

    const unsigned long long lt = (1ull << lane) - 1ull;
    int cnt = 0;
    #pragma unroll
    for (int t = 0; t < 4; ++t) {
        #pragma unroll
        for (int b = 0; b < 4; ++b) {
            float vb = (b == 0) ? av[t].x : (b == 1) ? av[t].y : (b == 2) ? av[t].z : av[t].w;
            cnt += __popcll(__ballot(vb > 0.0f));
        }
    }
    if (lane == 0) s_cnt[wv] = cnt;
    __syncthreads();
    int base = 0, total = 0;
    #pragma unroll
    for (int w = 0; w < 4; ++w) {
        if (w < wv) base += s_cnt[w];
        total += s_cnt[w];
    }
    const int d = total < MAXD ? total : MAXD;
    #pragma unroll
    for (int t = 0; t < 4; ++t) {
        #pragma unroll
        for (int b = 0; b < 4; ++b) {
            float vb = (b == 0) ? av[t].x : (b == 1) ? av[t].y : (b == 2) ? av[t].z : av[t].w;
            unsigned long long m = __ballot(vb > 0.0f);
            if (vb > 0.0f) {
                int p = base + __popcll(m & lt);
                if (p < MAXD) s_idx[p] = wv * 1024 + t * 256 + lane * 4 + b;
            }
            base += __popcll(m);
        }
    }
    __syncthreads();

    // ---- Phase B: scores ----
    const int jl = lane >> 3;      // neighbor sub-index, 0..7
    const int dgs = lane & 7;      // dim-group of 8
    const int h0 = wv, h1 = wv + 4;

    const unsigned short* qp = qkv + (size_t)n * 1536 + dgs * 8;
    uint4 qa = *(const uint4*)(qp + h0 * 64);
    uint4 qb = *(const uint4*)(qp + h1 * 64);
    const float a0 = blo(qa.x), a1 = bhi(qa.x), a2 = blo(qa.y), a3 = bhi(qa.y);
    const float a4 = blo(qa.z), a5 = bhi(qa.z), a6 = blo(qa.w), a7 = bhi(qa.w);
    const float b0 = blo(qb.x), b1 = bhi(qb.x), b2 = blo(qb.y), b3 = bhi(qb.y);
    const float b4 = blo(qb.z), b5 = bhi(qb.z), b6 = blo(qb.w), b7 = bhi(qb.w);

    uint4 ka = {0, 0, 0, 0}, kb = {0, 0, 0, 0};
    if (jl < d) {
        const unsigned short* p = qkv + (size_t)s_idx[jl] * 1536 + 512 + dgs * 8;
        ka = *(const uint4*)(p + h0 * 64);
        kb = *(const uint4*)(p + h1 * 64);
    }
    for (int j0 = 0; j0 < d; j0 += 8) {
        const uint4 ca = ka, cb = kb;
        const int jn = j0 + 8 + jl;
        if (jn < d) {
            const unsigned short* p = qkv + (size_t)s_idx[jn] * 1536 + 512 + dgs * 8;
            ka = *(const uint4*)(p + h0 * 64);
            kb = *(const uint4*)(p + h1 * 64);
        }
        const int jc = j0 + jl;
        float s0 = 0.f, s1 = 0.f;
        if (jc < d) {
            s0 = a0 * blo(ca.x) + a1 * bhi(ca.x) + a2 * blo(ca.y) + a3 * bhi(ca.y)
               + a4 * blo(ca.z) + a5 * bhi(ca.z) + a6 * blo(ca.w) + a7 * bhi(ca.w);
            s1 = b0 * blo(cb.x) + b1 * bhi(cb.x) + b2 * blo(cb.y) + b3 * bhi(cb.y)
               + b4 * blo(cb.z) + b5 * bhi(cb.z) + b6 * blo(cb.w) + b7 * bhi(cb.w);
        }
        s0 += __shfl_xor(s0, 1); s1 += __shfl_xor(s1, 1);
        s0 += __shfl_xor(s0, 2); s1 += __shfl_xor(s1, 2);
        s0 += __shfl_xor(s0, 4); s1 += __shfl_xor(s1, 4);
        if (dgs == 0 && jc < d) {
            s_p[h0][jc] = s0 * 0.125f;    // 1/sqrt(64)
            s_p[h1][jc] = s1 * 0.125f;
        }
    }

    // ---- softmax per head ----
    float inv0, inv1;
    #pragma unroll
    for (int hh = 0; hh < 2; ++hh) {
        float* sp = s_p[hh ? h1 : h0];
        float mx = -1e30f;
        for (int j = lane; j < d; j += 64) mx = fmaxf(mx, sp[j]);
        #pragma unroll
        for (int off = 32; off; off >>= 1) mx = fmaxf(mx, __shfl_xor(mx, off));
        float sum = 0.f;
        for (int j = lane; j < d; j += 64) {
            float e = __expf(sp[j] - mx);
            sp[j] = e;
            sum += e;
        }
        #pragma unroll
        for (int off = 32; off; off >>= 1) sum += __shfl_xor(sum, off);
        if (hh) inv1 = 1.0f / sum; else inv0 = 1.0f / sum;
    }

    // ---- accumulate o: 8 nbr-lanes x 8 dims/lane, uint4, prefetched ----
    float xa[8] = {}, ya[8] = {};
    uint4 va = {0, 0, 0, 0}, vb = {0, 0, 0, 0};
    if (jl < d) {
        const unsigned short* p = qkv + (size_t)s_idx[jl] * 1536 + 1024 + dgs * 8;
        va = *(const uint4*)(p + h0 * 64);
        vb = *(const uint4*)(p + h1 * 64);
    }
    for (int j0 = 0; j0 < d; j0 += 8) {
        const uint4 ca = va, cb = vb;
        const int jn = j0 + 8 + jl;
        if (jn < d) {
            const unsigned short* p = qkv + (size_t)s_idx[jn] * 1536 + 1024 + dgs * 8;
            va = *(const uint4*)(p + h0 * 64);
            vb = *(const uint4*)(p + h1 * 64);
        }
        const int jc = j0 + jl;
        if (jc < d) {
            const float p0 = s_p[h0][jc], p1 = s_p[h1][jc];
            xa[0] += p0 * blo(ca.x); xa[1] += p0 * bhi(ca.x);
            xa[2] += p0 * blo(ca.y); xa[3] += p0 * bhi(ca.y);
            xa[4] += p0 * blo(ca.z); xa[5] += p0 * bhi(ca.z);
            xa[6] += p0 * blo(ca.w); xa[7] += p0 * bhi(ca.w);
            ya[0] += p1 * blo(cb.x); ya[1] += p1 * bhi(cb.x);
            ya[2] += p1 * blo(cb.y); ya[3] += p1 * bhi(cb.y);
            ya[4] += p1 * blo(cb.z); ya[5] += p1 * bhi(cb.z);
            ya[6] += p1 * blo(cb.w); ya[7] += p1 * bhi(cb.w);
        }
    }
    #pragma unroll
    for (int t = 0; t < 8; ++t) {
        xa[t] += __shfl_xor(xa[t], 8);
        xa[t] += __shfl_xor(xa[t], 16);
        xa[t] += __shfl_xor(xa[t], 32);
        ya[t] += __shfl_xor(ya[t], 8);
        ya[t] += __shfl_xor(ya[t], 16);
        ya[t] += __shfl_xor(ya[t], 32);
    }
    if (jl == 0) {
        uint4 w0, w1;
        w0.x = (unsigned int)f2bf(xa[0] * inv0) | ((unsigned int)f2bf(xa[1] * inv0) << 16);
        w0.y = (unsigned int)f2bf(xa[2] * inv0) | ((unsigned int)f2bf(xa[3] * inv0) << 16);
        w0.z = (unsigned int)f2bf(xa[4] * inv0) | ((unsigned int)f2bf(xa[5] * inv0) << 16);
        w0.w = (unsigned int)f2bf(xa[6] * inv0) | ((unsigned int)f2bf(xa[7] * inv0) << 16);
        w1.x = (unsigned int)f2bf(ya[0] * inv1) | ((unsigned int)f2bf(ya[1] * inv1) << 16);
        w1.y = (unsigned int)f2bf(ya[2] * inv1) | ((unsigned int)f2bf(ya[3] * inv1) << 16);
        w1.z = (unsigned int)f2bf(ya[4] * inv1) | ((unsigned int)f2bf(ya[5] * inv1) << 16);
        w1.w = (unsigned int)f2bf(ya[6] * inv1) | ((unsigned int)f2bf(ya[7] * inv1) << 16);
        *(uint4*)(o + (size_t)n * 512 + h0 * 64 + dgs * 8) = w0;
        *(uint4*)(o + (size_t)n * 512 + h1 * 64 + dgs * 8) = w1;
    }
}

// ---------------------------------------------------------------------------
// BatchNorm apply, float4 (stats fused in the preceding GEMM epilogue).
// ---------------------------------------------------------------------------
__global__ __launch_bounds__(256) void bn_apply4(
    const float4* __restrict__ x, const float* __restrict__ sum,
    const float* __restrict__ sumsq, const float* __restrict__ g,
    const float* __restrict__ b, float4* __restrict__ yf,
    uint2* __restrict__ yb)
{
    const int i = blockIdx.x * 256 + threadIdx.x;
    const int c4 = i & 127;
    const float4 s4 = ((const float4*)sum)[c4];
    const float4 q4 = ((const float4*)sumsq)[c4];
    const float4 g4 = ((const float4*)g)[c4];
    const float4 b4 = ((const float4*)b)[c4];
    const float4 xv = x[i];
    const float kN = 1.0f / N_NODES;
    float4 r;
    { float m = s4.x * kN; r.x = g4.x * (xv.x - m) * rsqrtf(q4.x * kN - m * m + EPS) + b4.x; }
    { float m = s4.y * kN; r.y = g4.y * (xv.y - m) * rsqrtf(q4.y * kN - m * m + EPS) + b4.y; }
    { float m = s4.z * kN; r.z = g4.z * (xv.z - m) * rsqrtf(q4.z * kN - m * m + EPS) + b4.z; }
    { float m = s4.w * kN; r.w = g4.w * (xv.w - m) * rsqrtf(q4.w * kN - m * m + EPS) + b4.w; }
    if (yf) yf[i] = r;
    if (yb) {
        uint2 p;
        p.x = (unsigned int)f2bf(r.x) | ((unsigned int)f2bf(r.y) << 16);
        p.y = (unsigned int)f2bf(r.z) | ((unsigned int)f2bf(r.w) << 16);
        yb[i] = p;
    }
}

// ---------------------------------------------------------------------------

extern "C" void kernel_launch(void* const* d_in, const int* in_sizes, int n_in,
                              void* d_out, int out_size, void* d_ws, size_t ws_size,
                              hipStream_t stream)
{
    const float* A   = (const float*)d_in[0];
    const float* h   = (const float*)d_in[1];
    const float* Wq  = (const float*)d_in[2];
    const float* bq  = (const float*)d_in[3];
    const float* Wk  = (const float*)d_in[4];
    const float* bk  = (const float*)d_in[5];
    const float* Wv  = (const float*)d_in[6];
    const float* bv  = (const float*)d_in[7];
    const float* Wo  = (const float*)d_in[8];
    const float* bo  = (const float*)d_in[9];
    const float* g1  = (const float*)d_in[10];
    const float* b1g = (const float*)d_in[11];
    const float* g2  = (const float*)d_in[12];
    const float* b2g = (const float*)d_in[13];
    const float* W1  = (const float*)d_in[14];
    const float* b1  = (const float*)d_in[15];
    const float* W2  = (const float*)d_in[16];
    const float* b2  = (const float*)d_in[17];
    float* out = (float*)d_out;

    float* ws = (float*)d_ws;
    unsigned short* hb    = (unsigned short*)(ws);               // 4096x512 bf16 (frag)
    unsigned short* qkvb  = (unsigned short*)(ws + 1048576);     // 4096x1536 bf16
    unsigned short* o_bf  = (unsigned short*)(ws + 4194304);     // 4096x512 bf16
    unsigned short* wqkvT = (unsigned short*)(ws + 5242880);     // 1536x512 bf16 K-major
    unsigned short* woT   = (unsigned short*)(ws + 5636096);     // 512x512 bf16 K-major
    unsigned short* w1T   = (unsigned short*)(ws + 5767168);     // 1024x512 bf16 K-major
    unsigned short* w2T   = (unsigned short*)(ws + 6029312);     // 512x1024 bf16 K-major
    unsigned short* t_b   = (unsigned short*)(ws + 6291456);     // 4096x1024 bf16
    float* x1   = ws + 8388608;                                   // 4096x512 f32
    float* x2   = ws + 10485760;                                  // 4096x512 f32
    unsigned short* xb1_b = (unsigned short*)(ws + 12582912);    // 4096x512 bf16
    float* bqkv = ws + 13631488;                                  // 1536
    float* st   = ws + 13633024;                                  // 2048

    // --- fused prep ---
    prep_all<<<dim3(32, 32, 8), dim3(256), 0, stream>>>(
        Wq, Wk, Wv, Wo, W1, W2, h, bq, bk, bv,
        wqkvT, woT, w1T, w2T, (unsigned int*)hb, bqkv, st);

    // --- fused QKV projection: 768 blocks (3/CU), frag-packed A ---
    gemm_h<128, 0, true, 512><<<dim3(24, 32), dim3(256), 0, stream>>>(
        hb, wqkvT, bqkv, nullptr, nullptr, nullptr, qkvb, nullptr, nullptr, 1536);

    // --- sparse masked attention (inline adjacency) ---
    sparse_attn6<<<dim3(N_NODES), dim3(256), 0, stream>>>(A, qkvb, o_bf);

    // --- O projection + residual(h,f32) + BN1 stats: 512 blocks ---
    gemm_h<64, 2, false, 512><<<dim3(8, 64), dim3(256), 0, stream>>>(
        o_bf, woT, bo, h, nullptr, x1, nullptr, st, st + 512, 512);

    // --- BN1 apply -> bf16 only ---
    bn_apply4<<<dim3(2048), dim3(256), 0, stream>>>(
        (const float4*)x1, st, st + 512, g1, b1g, nullptr, (uint2*)xb1_b);

    // --- FFN1: 512 blocks ---
    gemm_h<128, 1, false, 512><<<dim3(16, 32), dim3(256), 0, stream>>>(
        xb1_b, w1T, b1, nullptr, nullptr, nullptr, t_b, nullptr, nullptr, 1024);

    // --- FFN2 + residual(xb1,bf16) + BN2 stats: 512 blocks ---
    gemm_h<64, 3, false, 1024><<<dim3(8, 64), dim3(256), 0, stream>>>(
        t_b, w2T, b2, nullptr, xb1_b, x2, nullptr, st + 1024, st + 1536, 512);

    // --- BN2 apply -> out ---
    bn_apply4<<<dim3(2048), dim3(256), 0, stream>>>(
        (const float4*)x2, st + 1024, st + 1536, g2, b2g, (float4*)out, nullptr);

    (void)in_sizes; (void)n_in; (void)out_size; (void)ws_size;
}